// Round 9
// baseline (338.070 us; speedup 1.0000x reference)
//
#include <hip/hip_runtime.h>

// Committee vote histogram:
//   logits[m,b,c] = x[b,:] . W[m,:,c] + bias[m,c]
//   votes[m,b]    = argmax_c logits
//   out[b,c]      = #{ m : votes[m,b] == c }   (float32)
//
// B=65536, D=512, M=16, C=10.
// R9: LDS-port pressure fix. R7/R8 walls (~250us) are set by LDS instruction
// throughput: 11 ds_reads per 40 FMAs (broadcast b128 ~4.7cyc, full b128
// ~12cyc). Here each wave owns FOUR 64-row groups (256 rows/block), so each
// W broadcast feeds 16 FMAs instead of 4: per-CU LDS cycles drop ~2.4x to
// ~parity with the FMA stream. KCHUNK=16 keeps the unrolled chunk body at
// the proven 640-FMA size; named acc0..acc3 (static indexing only); W via
// async global_load_lds (lane<40, linear dest); x register-staged prefetch.
// 256 blocks = exactly 1 block/CU, no tail.

#define DDIM    512
#define NCLS    10
#define ROWS    256                  // rows per block (4 groups of 64)
#define KCHUNK  16
#define NCHUNK  (DDIM / KCHUNK)      // 32
#define WCH4    40                   // float4 per model per chunk (160 floats)
#define WTOT4   (16 * WCH4)          // 640 float4 per chunk (all models)

typedef __attribute__((address_space(1))) const void global_cv;
typedef __attribute__((address_space(3))) void lds_v;

__global__ __launch_bounds__(1024, 4)
void committee_kernel(const float* __restrict__ x,
                      const float* __restrict__ W,
                      const float* __restrict__ bias,
                      float* __restrict__ out)
{
    // xs[buf][kq][row]: x[row0+row][ch*16 + 4*kq .. +3]; 257 stride (odd)
    __shared__ float4 xs[2][4][257];
    // ws4[buf][m*40 + kq*10 + q]: W[m] chunk, linear per model
    __shared__ float4 ws4[2][WTOT4];
    __shared__ int ihist[ROWS * NCLS];

    const int tid  = threadIdx.x;
    const int row0 = blockIdx.x * ROWS;

    for (int i = tid; i < ROWS * NCLS; i += 1024) ihist[i] = 0;

    const int m    = __builtin_amdgcn_readfirstlane(tid >> 6);  // wave = model
    const int lane = tid & 63;

    float acc0[NCLS], acc1[NCLS], acc2[NCLS], acc3[NCLS];
#pragma unroll
    for (int c = 0; c < NCLS; ++c) {
        const float bv = bias[m * NCLS + c];
        acc0[c] = bv; acc1[c] = bv; acc2[c] = bv; acc3[c] = bv;
    }

    // ---- x staging (register path): all 1024 threads, one float4 per chunk
    const int srow = tid >> 2;   // 0..255
    const int skq  = tid & 3;    // 0..3
    const float* gsrc = x + (size_t)(row0 + srow) * DDIM + (skq << 2);

    // ---- W staging (async DMA): wave m stages model m's 40-float4 slice.
    // global idx = m*1280 + ch*40 + lane (lanes 0..39); LDS dest =
    // wave-uniform &ws4[buf][m*40] + lane*16 (linear rule).
    const float4* W4  = reinterpret_cast<const float4*>(W);
    const float4* wg  = W4 + (size_t)m * 1280 + lane;

    // ---- prologue: stage chunk 0 (x direct, W async), prefetch x of chunk 1
    xs[0][skq][srow] = *reinterpret_cast<const float4*>(gsrc);
    if (lane < WCH4)
        __builtin_amdgcn_global_load_lds((global_cv*)wg,
                                         (lds_v*)&ws4[0][m * WCH4], 16, 0, 0);
    float4 px = *reinterpret_cast<const float4*>(gsrc + KCHUNK);

    for (int ch = 0; ch < NCHUNK; ++ch) {
        __syncthreads();           // drains vmcnt: staged W/x of buf[cur]
        const int cur = ch & 1;    // visible; prev readers of buf[cur^1] done

        if (ch + 1 < NCHUNK) {
            // issue async W stage for ch+1 (lands during this compute phase)
            if (lane < WCH4)
                __builtin_amdgcn_global_load_lds(
                    (global_cv*)(wg + (size_t)(ch + 1) * WCH4),
                    (lds_v*)&ws4[cur ^ 1][m * WCH4], 16, 0, 0);
            // x: write prefetched chunk ch+1, issue load for ch+2
            xs[cur ^ 1][skq][srow] = px;
            if (ch + 2 < NCHUNK)
                px = *reinterpret_cast<const float4*>(
                    gsrc + (size_t)(ch + 2) * KCHUNK);
        }

#pragma unroll
        for (int kq = 0; kq < 4; ++kq) {
            const float4 xv0 = xs[cur][kq][lane];
            const float4 xv1 = xs[cur][kq][64 + lane];
            const float4 xv2 = xs[cur][kq][128 + lane];
            const float4 xv3 = xs[cur][kq][192 + lane];
            const float xa0[4] = {xv0.x, xv0.y, xv0.z, xv0.w};
            const float xa1[4] = {xv1.x, xv1.y, xv1.z, xv1.w};
            const float xa2[4] = {xv2.x, xv2.y, xv2.z, xv2.w};
            const float xa3[4] = {xv3.x, xv3.y, xv3.z, xv3.w};
#pragma unroll
            for (int q = 0; q < 10; ++q) {
                // broadcast read: all lanes same address -> ~4.7cyc
                const float4 wv = ws4[cur][m * WCH4 + kq * 10 + q];
                const float warr[4] = {wv.x, wv.y, wv.z, wv.w};
#pragma unroll
                for (int k = 0; k < 4; ++k) {
                    const int f = 4 * q + k;      // flat (j,c): f = j*10 + c
                    const int j = f / 10;
                    const int c = f % 10;
                    const float w = warr[k];
                    acc0[c] = fmaf(xa0[j], w, acc0[c]);
                    acc1[c] = fmaf(xa1[j], w, acc1[c]);
                    acc2[c] = fmaf(xa2[j], w, acc2[c]);
                    acc3[c] = fmaf(xa3[j], w, acc3[c]);
                }
            }
        }
    }

    // argmax per row-group, first-occurrence-of-max semantics (strict >)
    {
        int best = 0; float bv = acc0[0];
#pragma unroll
        for (int c = 1; c < NCLS; ++c)
            if (acc0[c] > bv) { bv = acc0[c]; best = c; }
        atomicAdd(&ihist[lane * NCLS + best], 1);
    }
    {
        int best = 0; float bv = acc1[0];
#pragma unroll
        for (int c = 1; c < NCLS; ++c)
            if (acc1[c] > bv) { bv = acc1[c]; best = c; }
        atomicAdd(&ihist[(64 + lane) * NCLS + best], 1);
    }
    {
        int best = 0; float bv = acc2[0];
#pragma unroll
        for (int c = 1; c < NCLS; ++c)
            if (acc2[c] > bv) { bv = acc2[c]; best = c; }
        atomicAdd(&ihist[(128 + lane) * NCLS + best], 1);
    }
    {
        int best = 0; float bv = acc3[0];
#pragma unroll
        for (int c = 1; c < NCLS; ++c)
            if (acc3[c] > bv) { bv = acc3[c]; best = c; }
        atomicAdd(&ihist[(192 + lane) * NCLS + best], 1);
    }
    __syncthreads();

    for (int i = tid; i < ROWS * NCLS; i += 1024) {
        out[(size_t)row0 * NCLS + i] = (float)ihist[i];
    }
}

extern "C" void kernel_launch(void* const* d_in, const int* in_sizes, int n_in,
                              void* d_out, int out_size, void* d_ws, size_t ws_size,
                              hipStream_t stream) {
    const float* x  = (const float*)d_in[0];   // [65536, 512]
    const float* W  = (const float*)d_in[1];   // [16, 512, 10]
    const float* b  = (const float*)d_in[2];   // [16, 10]
    float* out      = (float*)d_out;           // [65536, 10]

    const int nblocks = 65536 / ROWS;          // 256
    committee_kernel<<<nblocks, 1024, 0, stream>>>(x, W, b, out);
}